// Round 1
// baseline (6382.574 us; speedup 1.0000x reference)
//
#include <hip/hip_runtime.h>

// QuantumDenseNet: 5-mode cutoff-6 CV circuit, batch 2048.
// Plan: (1) gates_kernel: precompute 80 beamsplitter 36x36 expm's + 40 folded
// single-mode gates (squeeze*rot, kerr*disp*rot). (2) dcol_kernel: per (b,mode)
// real expm column-0 for the initial displacement. (3) qnet_kernel: one block
// per batch item, psi in LDS, fiber-private in-place gate application.

__device__ __forceinline__ void cmadd(float &ax, float &ay, const float2 u, const float2 v) {
    ax = fmaf(u.x, v.x, ax);
    ax = fmaf(-u.y, v.y, ax);
    ay = fmaf(u.x, v.y, ay);
    ay = fmaf(u.y, v.x, ay);
}

// ---------------------------------------------------------------------------
// Gate precompute: blocks 0..79 -> BS gates (36x36 complex expm in LDS),
// block 80 -> 40 single-mode combined gates, one per thread (serial 6x6 expm).
// ---------------------------------------------------------------------------
__global__ void gates_kernel(const float* __restrict__ lin,
                             const float* __restrict__ act,
                             const float* __restrict__ lact,
                             float2* __restrict__ bs,
                             float2* __restrict__ sg)
{
    __shared__ float2 B0[1296];
    __shared__ float2 B1[1296];
    const int tid = threadIdx.x;

    if (blockIdx.x < 80) {
        // ---- beamsplitter gate g: layer l, half q, gate n ----
        const int g = blockIdx.x;
        const int l = g / 20;
        const int w = g % 20;
        const int q = w / 10;
        const int n = w % 10;
        const float theta = lin[l*63 + (q ? 29 : 0) + n];
        const float phi   = lin[l*63 + (q ? 39 : 10) + n];
        const float ts = theta * 0.015625f;            // theta / 2^6
        const float cp = cosf(phi), sp = sinf(phi);
        const float2 u  = make_float2( ts*cp, ts*sp);  //  ts * e^{+i phi}
        const float2 w2 = make_float2(-ts*cp, ts*sp);  // -ts * e^{-i phi}

        float2 *R = B0, *T = B1;
        for (int e = tid; e < 1296; e += 256)
            R[e] = make_float2((e % 37 == 0) ? 1.f : 0.f, 0.f);
        __syncthreads();

        // R = I + Hs @ R * (1/k), k = 16..1 ; Hs sparse (2 bands in 36-space)
        for (int k = 16; k >= 1; --k) {
            const float invk = 1.f / (float)k;
            for (int e = tid; e < 1296; e += 256) {
                const int row = e / 36, c = e - row*36;
                const int i = row / 6, j = row - (row/6)*6;
                float ax = 0.f, ay = 0.f;
                if (i < 5 && j > 0) {   // H[(i,j)][(i+1,j-1)] = e^{i phi} sqrt((i+1)j)
                    const float coef = sqrtf((float)((i+1)*j));
                    const float2 x = R[(row+5)*36 + c];
                    const float px = u.x*x.x - u.y*x.y;
                    const float py = u.x*x.y + u.y*x.x;
                    ax = fmaf(coef, px, ax); ay = fmaf(coef, py, ay);
                }
                if (i > 0 && j < 5) {   // H[(i,j)][(i-1,j+1)] = -e^{-i phi} sqrt(i(j+1))
                    const float coef = sqrtf((float)(i*(j+1)));
                    const float2 x = R[(row-5)*36 + c];
                    const float px = w2.x*x.x - w2.y*x.y;
                    const float py = w2.x*x.y + w2.y*x.x;
                    ax = fmaf(coef, px, ax); ay = fmaf(coef, py, ay);
                }
                T[e] = make_float2(((row == c) ? 1.f : 0.f) + ax*invk, ay*invk);
            }
            __syncthreads();
            float2* tmp = R; R = T; T = tmp;
        }
        // 6 squarings
        for (int s2 = 0; s2 < 6; ++s2) {
            for (int e = tid; e < 1296; e += 256) {
                const int row = e / 36, c = e - row*36;
                float ax = 0.f, ay = 0.f;
                #pragma unroll 6
                for (int k = 0; k < 36; ++k)
                    cmadd(ax, ay, R[row*36 + k], R[k*36 + c]);
                T[e] = make_float2(ax, ay);
            }
            __syncthreads();
            float2* tmp = R; R = T; T = tmp;
        }
        for (int e = tid; e < 1296; e += 256) bs[g*1296 + e] = R[e];
    } else {
        // ---- single-mode combined gates, thread t handles gate t ----
        const int t = tid;
        if (t >= 40) return;
        const int l  = t / 10;
        const int gi = t % 10;
        if (gi < 5) {
            // Sq[m] = squeeze(r) @ diag(e^{i rphi1 * n})
            const int m = gi;
            const float r    = lin[l*63 + 24 + m];
            const float rphi = (m < 4) ? lin[l*63 + 20 + m] : 0.f;
            float R[36], T[36];
            #pragma unroll
            for (int e = 0; e < 36; ++e) R[e] = (e % 7 == 0) ? 1.f : 0.f;
            float hp[4];
            #pragma unroll
            for (int i = 0; i < 4; ++i)
                hp[i] = 0.5f * r * sqrtf((float)((i+1)*(i+2))) * 0.015625f;
            for (int k = 16; k >= 1; --k) {
                const float invk = 1.f / (float)k;
                #pragma unroll
                for (int i = 0; i < 6; ++i) {
                    #pragma unroll
                    for (int c = 0; c < 6; ++c) {
                        float a = 0.f;
                        if (i < 4)  a = fmaf( hp[i],   R[(i+2)*6 + c], a);
                        if (i >= 2) a = fmaf(-hp[i-2], R[(i-2)*6 + c], a);
                        T[i*6+c] = ((i == c) ? 1.f : 0.f) + a*invk;
                    }
                }
                #pragma unroll
                for (int e = 0; e < 36; ++e) R[e] = T[e];
            }
            for (int s2 = 0; s2 < 6; ++s2) {
                #pragma unroll
                for (int i = 0; i < 6; ++i) {
                    #pragma unroll
                    for (int c = 0; c < 6; ++c) {
                        float a = 0.f;
                        #pragma unroll
                        for (int k = 0; k < 6; ++k) a = fmaf(R[i*6+k], R[k*6+c], a);
                        T[i*6+c] = a;
                    }
                }
                #pragma unroll
                for (int e = 0; e < 36; ++e) R[e] = T[e];
            }
            float2* outp = sg + (l*10 + m)*36;
            #pragma unroll
            for (int c = 0; c < 6; ++c) {
                const float cc = cosf(rphi * (float)c), ss = sinf(rphi * (float)c);
                #pragma unroll
                for (int o = 0; o < 6; ++o)
                    outp[o*6 + c] = make_float2(R[o*6+c]*cc, R[o*6+c]*ss);
            }
        } else {
            // Dp[m] = diag(e^{i kap n^2}) @ disp(dr,dp) @ diag(e^{i rphi2 n})
            const int m = gi - 5;
            const float dr   = lin[l*63 + 53 + m];
            const float dp   = lin[l*63 + 58 + m];
            const float rphi = (m < 4) ? lin[l*63 + 49 + m] : 0.f;
            const float kap  = (l < 3) ? act[l*5 + m] : ((m < 2) ? lact[m] : 0.f);
            const float2 al = make_float2(dr * cosf(dp), dr * sinf(dp));
            float2 R[36], T[36];
            #pragma unroll
            for (int e = 0; e < 36; ++e)
                R[e] = make_float2((e % 7 == 0) ? 1.f : 0.f, 0.f);
            float2 cm[6], cpb[6];
            #pragma unroll
            for (int i = 0; i < 6; ++i) {
                const float sm  = sqrtf((float)i)     * 0.015625f; // row i uses R[i-1]: +al*sqrt(i)/64
                const float sp2 = sqrtf((float)(i+1)) * 0.015625f; // row i uses R[i+1]: -conj(al)*sqrt(i+1)/64
                cm[i]  = make_float2( al.x*sm,  al.y*sm);
                cpb[i] = make_float2(-al.x*sp2, al.y*sp2);
            }
            for (int k = 16; k >= 1; --k) {
                const float invk = 1.f / (float)k;
                #pragma unroll
                for (int i = 0; i < 6; ++i) {
                    #pragma unroll
                    for (int c = 0; c < 6; ++c) {
                        float ax = 0.f, ay = 0.f;
                        if (i >= 1) cmadd(ax, ay, cm[i],  R[(i-1)*6 + c]);
                        if (i < 5)  cmadd(ax, ay, cpb[i], R[(i+1)*6 + c]);
                        T[i*6+c] = make_float2(((i == c) ? 1.f : 0.f) + ax*invk, ay*invk);
                    }
                }
                #pragma unroll
                for (int e = 0; e < 36; ++e) R[e] = T[e];
            }
            for (int s2 = 0; s2 < 6; ++s2) {
                #pragma unroll
                for (int i = 0; i < 6; ++i) {
                    #pragma unroll
                    for (int c = 0; c < 6; ++c) {
                        float ax = 0.f, ay = 0.f;
                        #pragma unroll
                        for (int k = 0; k < 6; ++k) cmadd(ax, ay, R[i*6+k], R[k*6+c]);
                        T[i*6+c] = make_float2(ax, ay);
                    }
                }
                #pragma unroll
                for (int e = 0; e < 36; ++e) R[e] = T[e];
            }
            float2* outp = sg + (l*10 + 5 + m)*36;
            #pragma unroll
            for (int o = 0; o < 6; ++o) {
                const float ko = kap * (float)(o*o);
                const float2 kp = make_float2(cosf(ko), sinf(ko));
                #pragma unroll
                for (int c = 0; c < 6; ++c) {
                    const float rc = rphi * (float)c;
                    const float2 rp = make_float2(cosf(rc), sinf(rc));
                    const float2 z = R[o*6 + c];
                    const float2 t1 = make_float2(kp.x*z.x - kp.y*z.y, kp.x*z.y + kp.y*z.x);
                    outp[o*6 + c] = make_float2(t1.x*rp.x - t1.y*rp.y, t1.x*rp.y + t1.y*rp.x);
                }
            }
        }
    }
}

// ---------------------------------------------------------------------------
// Initial displacement (phi=0 -> real expm): column 0 per (batch, mode).
// ---------------------------------------------------------------------------
__global__ void dcol_kernel(const float* __restrict__ x,
                            float* __restrict__ dcol, const int total)
{
    const int i = blockIdx.x * 256 + threadIdx.x;
    if (i >= total) return;
    const float xv = x[i];
    float a[5];
    #pragma unroll
    for (int j = 0; j < 5; ++j) a[j] = xv * sqrtf((float)(j+1)) * 0.015625f;
    // Hs[r][r-1] = a[r-1]; Hs[r][r+1] = -a[r]
    float R[36], T[36];
    #pragma unroll
    for (int e = 0; e < 36; ++e) R[e] = (e % 7 == 0) ? 1.f : 0.f;
    for (int k = 16; k >= 1; --k) {
        const float invk = 1.f / (float)k;
        #pragma unroll
        for (int r = 0; r < 6; ++r) {
            #pragma unroll
            for (int c = 0; c < 6; ++c) {
                float acc = 0.f;
                if (r >= 1) acc = fmaf( a[r-1], R[(r-1)*6 + c], acc);
                if (r < 5)  acc = fmaf(-a[r],   R[(r+1)*6 + c], acc);
                T[r*6+c] = ((r == c) ? 1.f : 0.f) + acc*invk;
            }
        }
        #pragma unroll
        for (int e = 0; e < 36; ++e) R[e] = T[e];
    }
    for (int s2 = 0; s2 < 6; ++s2) {
        #pragma unroll
        for (int r = 0; r < 6; ++r) {
            #pragma unroll
            for (int c = 0; c < 6; ++c) {
                float acc = 0.f;
                #pragma unroll
                for (int k = 0; k < 6; ++k) acc = fmaf(R[r*6+k], R[k*6+c], acc);
                T[r*6+c] = acc;
            }
        }
        #pragma unroll
        for (int e = 0; e < 36; ++e) R[e] = T[e];
    }
    #pragma unroll
    for (int j = 0; j < 6; ++j) dcol[i*6 + j] = R[j*6 + 0];
}

// ---------------------------------------------------------------------------
// Main circuit kernel: one block = one batch item; psi in LDS (7776 float2).
// ---------------------------------------------------------------------------
template<int S>
__device__ __forceinline__ void apply2_t(const float2* __restrict__ U,
                                         float2* __restrict__ psi,
                                         float2* __restrict__ stage,
                                         const int tid)
{
    // pair of modes with inner stride S (outer mode stride 6S); fiber len 36
    float2 v[36];
    int base = 0;
    const bool active = (tid < 216);
    if (active) {
        const int q = tid / S;
        const int r = tid - q * S;
        base = q * (36 * S) + r;
        #pragma unroll
        for (int c = 0; c < 36; ++c) v[c] = psi[base + c * S];
    }
    for (int ch = 0; ch < 4; ++ch) {         // 4 chunks of 9 output rows
        __syncthreads();                      // stage free for reuse
        {
            int idx = tid;
            stage[idx] = U[ch*324 + idx];
            idx += 256;
            if (idx < 324) stage[idx] = U[ch*324 + idx];
        }
        __syncthreads();
        if (active) {
            #pragma unroll 3
            for (int o = 0; o < 9; ++o) {
                const float2* srow = stage + o*36;
                float ax = 0.f, ay = 0.f;
                #pragma unroll
                for (int i = 0; i < 36; ++i) cmadd(ax, ay, srow[i], v[i]);
                psi[base + (ch*9 + o)*S] = make_float2(ax, ay);
            }
        }
    }
    __syncthreads();
}

template<int S>
__device__ __forceinline__ void apply1_t(const float2* __restrict__ G,
                                         float2* __restrict__ psi,
                                         const int tid)
{
    float2 g[36];
    #pragma unroll
    for (int k = 0; k < 36; ++k) g[k] = G[k];   // block-uniform loads
    for (int f = tid; f < 1296; f += 256) {
        const int q = f / S;
        const int r = f - q*S;
        const int base = q*(6*S) + r;
        float2 v[6];
        #pragma unroll
        for (int j = 0; j < 6; ++j) v[j] = psi[base + j*S];
        #pragma unroll
        for (int o = 0; o < 6; ++o) {
            float ax = 0.f, ay = 0.f;
            #pragma unroll
            for (int j = 0; j < 6; ++j) cmadd(ax, ay, g[o*6 + j], v[j]);
            psi[base + o*S] = make_float2(ax, ay);
        }
    }
    __syncthreads();
}

__global__ __launch_bounds__(256, 2)
void qnet_kernel(const float2* __restrict__ bs,
                 const float2* __restrict__ sg,
                 const float* __restrict__ dcol,
                 float* __restrict__ out)
{
    __shared__ float2 psi[7776];    // 62208 B
    __shared__ float2 stage[324];   //  2592 B
    __shared__ float  red[8];
    const int tid = threadIdx.x;
    const int b   = blockIdx.x;

    // initial state: outer product of displacement columns
    float* stf = (float*)stage;
    if (tid < 30) stf[tid] = dcol[b*30 + tid];
    __syncthreads();
    for (int e = tid; e < 7776; e += 256) {
        int t = e;
        const int i4 = t % 6; t /= 6;
        const int i3 = t % 6; t /= 6;
        const int i2 = t % 6; t /= 6;
        const int i1 = t % 6; t /= 6;
        const int i0 = t;
        const float val = stf[i0] * stf[6+i1] * stf[12+i2] * stf[18+i3] * stf[24+i4];
        psi[e] = make_float2(val, 0.f);
    }
    __syncthreads();

    for (int l = 0; l < 4; ++l) {
        const float2* bsl = bs + l * 20 * 1296;
        const float2* sgl = sg + l * 10 * 36;
        for (int half = 0; half < 2; ++half) {
            const float2* bh = bsl + half * 10 * 1296;
            // BS rail order k = {0,2,1,3,0,2,1,3,0,2} -> strides 6^(3-k)
            apply2_t<216>(bh + 0*1296, psi, stage, tid);
            apply2_t<  6>(bh + 1*1296, psi, stage, tid);
            apply2_t< 36>(bh + 2*1296, psi, stage, tid);
            apply2_t<  1>(bh + 3*1296, psi, stage, tid);
            apply2_t<216>(bh + 4*1296, psi, stage, tid);
            apply2_t<  6>(bh + 5*1296, psi, stage, tid);
            apply2_t< 36>(bh + 6*1296, psi, stage, tid);
            apply2_t<  1>(bh + 7*1296, psi, stage, tid);
            apply2_t<216>(bh + 8*1296, psi, stage, tid);
            apply2_t<  6>(bh + 9*1296, psi, stage, tid);
            const float2* sh = sgl + half * 5 * 36;
            apply1_t<1296>(sh + 0*36, psi, tid);
            apply1_t< 216>(sh + 1*36, psi, tid);
            apply1_t<  36>(sh + 2*36, psi, tid);
            apply1_t<   6>(sh + 3*36, psi, tid);
            apply1_t<   1>(sh + 4*36, psi, tid);
        }
    }

    // <psi| X psi> on modes 0,1:  2 * sum_j sqrt(j+1) Re(conj(psi_j) psi_{j+1})
    float s0 = 0.f, s1 = 0.f;
    for (int f = tid; f < 1296; f += 256) {
        #pragma unroll
        for (int j = 0; j < 5; ++j) {
            const float2 p0 = psi[f + j*1296];
            const float2 p1 = psi[f + (j+1)*1296];
            s0 = fmaf(sqrtf((float)(j+1)), fmaf(p0.y, p1.y, p0.x*p1.x), s0);
        }
    }
    for (int f = tid; f < 1296; f += 256) {
        const int q = f / 216;
        const int r = f - q*216;
        const int base = q*1296 + r;
        #pragma unroll
        for (int j = 0; j < 5; ++j) {
            const float2 p0 = psi[base + j*216];
            const float2 p1 = psi[base + (j+1)*216];
            s1 = fmaf(sqrtf((float)(j+1)), fmaf(p0.y, p1.y, p0.x*p1.x), s1);
        }
    }
    #pragma unroll
    for (int off = 32; off > 0; off >>= 1) {
        s0 += __shfl_down(s0, off, 64);
        s1 += __shfl_down(s1, off, 64);
    }
    if ((tid & 63) == 0) { red[(tid>>6)*2] = s0; red[(tid>>6)*2 + 1] = s1; }
    __syncthreads();
    if (tid == 0) {
        out[b*2 + 0] = 2.f*(red[0] + red[2] + red[4] + red[6]);
        out[b*2 + 1] = 2.f*(red[1] + red[3] + red[5] + red[7]);
    }
}

// ---------------------------------------------------------------------------
extern "C" void kernel_launch(void* const* d_in, const int* in_sizes, int n_in,
                              void* d_out, int out_size, void* d_ws, size_t ws_size,
                              hipStream_t stream)
{
    const float* x    = (const float*)d_in[0];   // (B, 5)
    const float* lin  = (const float*)d_in[1];   // (4, 63)
    const float* act  = (const float*)d_in[2];   // (3, 5)
    const float* lact = (const float*)d_in[3];   // (5,)
    float* out = (float*)d_out;                  // (B, 2) float32

    const int B = in_sizes[0] / 5;

    // ws layout: 80 BS gates (1296 c64) | 40 single gates (36 c64) | B*5*6 dcol f32
    float2* bs = (float2*)d_ws;
    float2* sg = bs + 80*1296;
    float*  dc = (float*)(sg + 40*36);

    gates_kernel<<<dim3(81), dim3(256), 0, stream>>>(lin, act, lact, bs, sg);
    const int total = B * 5;
    dcol_kernel<<<dim3((total + 255)/256), dim3(256), 0, stream>>>(x, dc, total);
    qnet_kernel<<<dim3(B), dim3(256), 0, stream>>>(bs, sg, dc, out);
}

// Round 2
// 1476.315 us; speedup vs baseline: 4.3233x; 4.3233x over previous
//
#include <hip/hip_runtime.h>

// QuantumDenseNet: 5-mode cutoff-6 CV circuit, batch 2048.
// R2: (a) beamsplitter gates applied in block-diagonal (photon-number
// conserving) packed form: 146 cMACs/fiber vs 1296 dense (8.9x FLOP cut).
// (b) gate matrices read via uniform (scalar) loads from global - no LDS
// staging, 1 barrier per gate (fiber-ownership partition). (c) psi strides
// padded {1332,222,37,6,1} to spread LDS bank accesses.

__device__ __forceinline__ void cmadd(float &ax, float &ay, const float2 u, const float2 v) {
    ax = fmaf(u.x, v.x, ax);
    ax = fmaf(-u.y, v.y, ax);
    ay = fmaf(u.x, v.y, ay);
    ay = fmaf(u.y, v.x, ay);
}

// block-diagonal structure of the 36x36 BS gate (total photon number n=0..10)
constexpr int BS_SN[11]  = {1,2,3,4,5,6,5,4,3,2,1};
constexpr int BS_OFF[11] = {0,1,5,14,30,55,91,116,132,141,145};
// padded mode strides (float2 units); mode2 padded 36->37
constexpr int MS[5] = {1332, 222, 37, 6, 1};
// apply2 spectator strides (descending) for gate pair (K,K+1)
constexpr int SP2[4][3] = {
    {37, 6, 1},       // K=0: spectators 2,3,4
    {1332, 6, 1},     // K=1: spectators 0,3,4
    {1332, 222, 1},   // K=2: spectators 0,1,4
    {1332, 222, 37},  // K=3: spectators 0,1,2
};
// apply1 spectator strides (descending) for mode M
constexpr int SP1[5][4] = {
    {222, 37, 6, 1},
    {1332, 37, 6, 1},
    {1332, 222, 6, 1},
    {1332, 222, 37, 1},
    {1332, 222, 37, 6},
};

// runtime-indexed copy for gates_kernel packing
__device__ const int d_BS_OFF[12] = {0,1,5,14,30,55,91,116,132,141,145,146};
__device__ const int d_BS_SN[11]  = {1,2,3,4,5,6,5,4,3,2,1};

// ---------------------------------------------------------------------------
// Gate precompute: blocks 0..79 -> BS gates (36x36 expm in LDS, then packed
// block-diagonal, 146 complex each), block 80 -> 40 single-mode gates.
// ---------------------------------------------------------------------------
__global__ void gates_kernel(const float* __restrict__ lin,
                             const float* __restrict__ act,
                             const float* __restrict__ lact,
                             float2* __restrict__ bs,
                             float2* __restrict__ sg)
{
    __shared__ float2 B0[1296];
    __shared__ float2 B1[1296];
    const int tid = threadIdx.x;

    if (blockIdx.x < 80) {
        const int g = blockIdx.x;
        const int l = g / 20;
        const int w = g % 20;
        const int q = w / 10;
        const int n = w % 10;
        const float theta = lin[l*63 + (q ? 29 : 0) + n];
        const float phi   = lin[l*63 + (q ? 39 : 10) + n];
        const float ts = theta * 0.015625f;
        const float cp = cosf(phi), sp = sinf(phi);
        const float2 u  = make_float2( ts*cp, ts*sp);
        const float2 w2 = make_float2(-ts*cp, ts*sp);

        float2 *R = B0, *T = B1;
        for (int e = tid; e < 1296; e += 256)
            R[e] = make_float2((e % 37 == 0) ? 1.f : 0.f, 0.f);
        __syncthreads();

        for (int k = 16; k >= 1; --k) {
            const float invk = 1.f / (float)k;
            for (int e = tid; e < 1296; e += 256) {
                const int row = e / 36, c = e - row*36;
                const int i = row / 6, j = row - (row/6)*6;
                float ax = 0.f, ay = 0.f;
                if (i < 5 && j > 0) {
                    const float coef = sqrtf((float)((i+1)*j));
                    const float2 x = R[(row+5)*36 + c];
                    const float px = u.x*x.x - u.y*x.y;
                    const float py = u.x*x.y + u.y*x.x;
                    ax = fmaf(coef, px, ax); ay = fmaf(coef, py, ay);
                }
                if (i > 0 && j < 5) {
                    const float coef = sqrtf((float)(i*(j+1)));
                    const float2 x = R[(row-5)*36 + c];
                    const float px = w2.x*x.x - w2.y*x.y;
                    const float py = w2.x*x.y + w2.y*x.x;
                    ax = fmaf(coef, px, ax); ay = fmaf(coef, py, ay);
                }
                T[e] = make_float2(((row == c) ? 1.f : 0.f) + ax*invk, ay*invk);
            }
            __syncthreads();
            float2* tmp = R; R = T; T = tmp;
        }
        for (int s2 = 0; s2 < 6; ++s2) {
            for (int e = tid; e < 1296; e += 256) {
                const int row = e / 36, c = e - row*36;
                float ax = 0.f, ay = 0.f;
                #pragma unroll 6
                for (int k = 0; k < 36; ++k)
                    cmadd(ax, ay, R[row*36 + k], R[k*36 + c]);
                T[e] = make_float2(ax, ay);
            }
            __syncthreads();
            float2* tmp = R; R = T; T = tmp;
        }
        // pack block-diagonal: 146 complex per gate
        for (int idx = tid; idx < 146; idx += 256) {
            int nn = 0;
            while (idx >= d_BS_OFF[nn+1]) ++nn;
            const int sn  = d_BS_SN[nn];
            const int rel = idx - d_BS_OFF[nn];
            const int p = rel / sn, qq = rel % sn;
            const int imin = (nn > 5) ? (nn - 5) : 0;
            const int row = 5*(imin + p)  + nn;
            const int col = 5*(imin + qq) + nn;
            bs[g*146 + idx] = R[row*36 + col];
        }
    } else {
        const int t = tid;
        if (t >= 40) return;
        const int l  = t / 10;
        const int gi = t % 10;
        if (gi < 5) {
            // Sq[m] = squeeze(r) @ diag(e^{i rphi1 * n})
            const int m = gi;
            const float r    = lin[l*63 + 24 + m];
            const float rphi = (m < 4) ? lin[l*63 + 20 + m] : 0.f;
            float R[36], T[36];
            #pragma unroll
            for (int e = 0; e < 36; ++e) R[e] = (e % 7 == 0) ? 1.f : 0.f;
            float hp[4];
            #pragma unroll
            for (int i = 0; i < 4; ++i)
                hp[i] = 0.5f * r * sqrtf((float)((i+1)*(i+2))) * 0.015625f;
            for (int k = 16; k >= 1; --k) {
                const float invk = 1.f / (float)k;
                #pragma unroll
                for (int i = 0; i < 6; ++i) {
                    #pragma unroll
                    for (int c = 0; c < 6; ++c) {
                        float a = 0.f;
                        if (i < 4)  a = fmaf( hp[i],   R[(i+2)*6 + c], a);
                        if (i >= 2) a = fmaf(-hp[i-2], R[(i-2)*6 + c], a);
                        T[i*6+c] = ((i == c) ? 1.f : 0.f) + a*invk;
                    }
                }
                #pragma unroll
                for (int e = 0; e < 36; ++e) R[e] = T[e];
            }
            for (int s2 = 0; s2 < 6; ++s2) {
                #pragma unroll
                for (int i = 0; i < 6; ++i) {
                    #pragma unroll
                    for (int c = 0; c < 6; ++c) {
                        float a = 0.f;
                        #pragma unroll
                        for (int k = 0; k < 6; ++k) a = fmaf(R[i*6+k], R[k*6+c], a);
                        T[i*6+c] = a;
                    }
                }
                #pragma unroll
                for (int e = 0; e < 36; ++e) R[e] = T[e];
            }
            float2* outp = sg + (l*10 + m)*36;
            #pragma unroll
            for (int c = 0; c < 6; ++c) {
                const float cc = cosf(rphi * (float)c), ss = sinf(rphi * (float)c);
                #pragma unroll
                for (int o = 0; o < 6; ++o)
                    outp[o*6 + c] = make_float2(R[o*6+c]*cc, R[o*6+c]*ss);
            }
        } else {
            // Dp[m] = diag(e^{i kap n^2}) @ disp(dr,dp) @ diag(e^{i rphi2 n})
            const int m = gi - 5;
            const float dr   = lin[l*63 + 53 + m];
            const float dp   = lin[l*63 + 58 + m];
            const float rphi = (m < 4) ? lin[l*63 + 49 + m] : 0.f;
            const float kap  = (l < 3) ? act[l*5 + m] : ((m < 2) ? lact[m] : 0.f);
            const float2 al = make_float2(dr * cosf(dp), dr * sinf(dp));
            float2 R[36], T[36];
            #pragma unroll
            for (int e = 0; e < 36; ++e)
                R[e] = make_float2((e % 7 == 0) ? 1.f : 0.f, 0.f);
            float2 cm[6], cpb[6];
            #pragma unroll
            for (int i = 0; i < 6; ++i) {
                const float sm  = sqrtf((float)i)     * 0.015625f;
                const float sp2 = sqrtf((float)(i+1)) * 0.015625f;
                cm[i]  = make_float2( al.x*sm,  al.y*sm);
                cpb[i] = make_float2(-al.x*sp2, al.y*sp2);
            }
            for (int k = 16; k >= 1; --k) {
                const float invk = 1.f / (float)k;
                #pragma unroll
                for (int i = 0; i < 6; ++i) {
                    #pragma unroll
                    for (int c = 0; c < 6; ++c) {
                        float ax = 0.f, ay = 0.f;
                        if (i >= 1) cmadd(ax, ay, cm[i],  R[(i-1)*6 + c]);
                        if (i < 5)  cmadd(ax, ay, cpb[i], R[(i+1)*6 + c]);
                        T[i*6+c] = make_float2(((i == c) ? 1.f : 0.f) + ax*invk, ay*invk);
                    }
                }
                #pragma unroll
                for (int e = 0; e < 36; ++e) R[e] = T[e];
            }
            for (int s2 = 0; s2 < 6; ++s2) {
                #pragma unroll
                for (int i = 0; i < 6; ++i) {
                    #pragma unroll
                    for (int c = 0; c < 6; ++c) {
                        float ax = 0.f, ay = 0.f;
                        #pragma unroll
                        for (int k = 0; k < 6; ++k) cmadd(ax, ay, R[i*6+k], R[k*6+c]);
                        T[i*6+c] = make_float2(ax, ay);
                    }
                }
                #pragma unroll
                for (int e = 0; e < 36; ++e) R[e] = T[e];
            }
            float2* outp = sg + (l*10 + 5 + m)*36;
            #pragma unroll
            for (int o = 0; o < 6; ++o) {
                const float ko = kap * (float)(o*o);
                const float2 kp = make_float2(cosf(ko), sinf(ko));
                #pragma unroll
                for (int c = 0; c < 6; ++c) {
                    const float rc = rphi * (float)c;
                    const float2 rp = make_float2(cosf(rc), sinf(rc));
                    const float2 z = R[o*6 + c];
                    const float2 t1 = make_float2(kp.x*z.x - kp.y*z.y, kp.x*z.y + kp.y*z.x);
                    outp[o*6 + c] = make_float2(t1.x*rp.x - t1.y*rp.y, t1.x*rp.y + t1.y*rp.x);
                }
            }
        }
    }
}

// ---------------------------------------------------------------------------
// Initial displacement (phi=0 -> real expm): column 0 per (batch, mode).
// ---------------------------------------------------------------------------
__global__ void dcol_kernel(const float* __restrict__ x,
                            float* __restrict__ dcol, const int total)
{
    const int i = blockIdx.x * 256 + threadIdx.x;
    if (i >= total) return;
    const float xv = x[i];
    float a[5];
    #pragma unroll
    for (int j = 0; j < 5; ++j) a[j] = xv * sqrtf((float)(j+1)) * 0.015625f;
    float R[36], T[36];
    #pragma unroll
    for (int e = 0; e < 36; ++e) R[e] = (e % 7 == 0) ? 1.f : 0.f;
    for (int k = 16; k >= 1; --k) {
        const float invk = 1.f / (float)k;
        #pragma unroll
        for (int r = 0; r < 6; ++r) {
            #pragma unroll
            for (int c = 0; c < 6; ++c) {
                float acc = 0.f;
                if (r >= 1) acc = fmaf( a[r-1], R[(r-1)*6 + c], acc);
                if (r < 5)  acc = fmaf(-a[r],   R[(r+1)*6 + c], acc);
                T[r*6+c] = ((r == c) ? 1.f : 0.f) + acc*invk;
            }
        }
        #pragma unroll
        for (int e = 0; e < 36; ++e) R[e] = T[e];
    }
    for (int s2 = 0; s2 < 6; ++s2) {
        #pragma unroll
        for (int r = 0; r < 6; ++r) {
            #pragma unroll
            for (int c = 0; c < 6; ++c) {
                float acc = 0.f;
                #pragma unroll
                for (int k = 0; k < 6; ++k) acc = fmaf(R[r*6+k], R[k*6+c], acc);
                T[r*6+c] = acc;
            }
        }
        #pragma unroll
        for (int e = 0; e < 36; ++e) R[e] = T[e];
    }
    #pragma unroll
    for (int j = 0; j < 6; ++j) dcol[i*6 + j] = R[j*6 + 0];
}

// ---------------------------------------------------------------------------
// Main kernel building blocks
// ---------------------------------------------------------------------------

// Recursive over photon-number blocks n: per block read sn inputs, sn^2 cMAC,
// write sn outputs (guarded). All psi indices compile-time folded.
template<int K, int n>
struct BDBlock {
    static __device__ __forceinline__ void run(const float2* __restrict__ U,
                                               float2* __restrict__ psi,
                                               const int base, const bool act) {
        constexpr int SA = MS[K], SB = MS[K+1];
        constexpr int sn = BS_SN[n], uoff = BS_OFF[n];
        constexpr int imin = (n > 5) ? (n - 5) : 0;
        float2 vb[sn];
        #pragma unroll
        for (int q = 0; q < sn; ++q) {
            const int c = 5*(imin + q) + n;
            vb[q] = psi[base + (c/6)*SA + (c%6)*SB];
        }
        float2 ob[sn];
        #pragma unroll
        for (int p = 0; p < sn; ++p) {
            float ax = 0.f, ay = 0.f;
            #pragma unroll
            for (int q = 0; q < sn; ++q)
                cmadd(ax, ay, U[uoff + p*sn + q], vb[q]);
            ob[p] = make_float2(ax, ay);
        }
        if (act) {
            #pragma unroll
            for (int p = 0; p < sn; ++p) {
                const int c = 5*(imin + p) + n;
                psi[base + (c/6)*SA + (c%6)*SB] = ob[p];
            }
        }
        BDBlock<K, n+1>::run(U, psi, base, act);
    }
};
template<int K>
struct BDBlock<K, 11> {
    static __device__ __forceinline__ void run(const float2*, float2*, int, bool) {}
};

template<int K>
__device__ __forceinline__ void apply2_bd(const float2* __restrict__ U,
                                          float2* __restrict__ psi, const int tid)
{
    const int f  = (tid < 216) ? tid : 215;
    const int d0 = f / 36, rem = f - d0*36;
    const int d1 = rem / 6, d2 = rem - d1*6;
    const int base = d0*SP2[K][0] + d1*SP2[K][1] + d2*SP2[K][2];
    const bool act = tid < 216;
    BDBlock<K, 0>::run(U, psi, base, act);
    __syncthreads();
}

template<int M5>
__device__ __forceinline__ void apply1_u(const float2* __restrict__ G,
                                         float2* __restrict__ psi, const int tid)
{
    constexpr int SM = MS[M5];
    float2 g[36];
    #pragma unroll
    for (int k = 0; k < 36; ++k) g[k] = G[k];   // block-uniform -> scalar loads
    for (int it = 0; it < 6; ++it) {
        const int fr = tid + it*256;
        const bool act = fr < 1296;
        const int f  = act ? fr : 1295;
        const int d0 = f / 216, r0 = f - d0*216;
        const int d1 = r0 / 36, r1 = r0 - d1*36;
        const int d2 = r1 / 6,  d3 = r1 - d2*6;
        const int base = d0*SP1[M5][0] + d1*SP1[M5][1] + d2*SP1[M5][2] + d3*SP1[M5][3];
        float2 v6[6];
        #pragma unroll
        for (int j = 0; j < 6; ++j) v6[j] = psi[base + j*SM];
        float2 o6[6];
        #pragma unroll
        for (int o = 0; o < 6; ++o) {
            float ax = 0.f, ay = 0.f;
            #pragma unroll
            for (int j = 0; j < 6; ++j) cmadd(ax, ay, g[o*6 + j], v6[j]);
            o6[o] = make_float2(ax, ay);
        }
        if (act) {
            #pragma unroll
            for (int o = 0; o < 6; ++o) psi[base + o*SM] = o6[o];
        }
    }
    __syncthreads();
}

__global__ __launch_bounds__(256, 2)
void qnet_kernel(const float2* __restrict__ bs,
                 const float2* __restrict__ sg,
                 const float* __restrict__ dcol,
                 float* __restrict__ out)
{
    __shared__ float2 psi[7992];   // padded strides {1332,222,37,6,1}
    __shared__ float  stf[30];
    __shared__ float  red[8];
    const int tid = threadIdx.x;
    const int b   = blockIdx.x;

    if (tid < 30) stf[tid] = dcol[b*30 + tid];
    __syncthreads();
    for (int e = tid; e < 7776; e += 256) {
        int t = e;
        const int i4 = t % 6; t /= 6;
        const int i3 = t % 6; t /= 6;
        const int i2 = t % 6; t /= 6;
        const int i1 = t % 6; t /= 6;
        const int i0 = t;
        const int addr = i0*1332 + i1*222 + i2*37 + i3*6 + i4;
        psi[addr] = make_float2(stf[i0]*stf[6+i1]*stf[12+i2]*stf[18+i3]*stf[24+i4], 0.f);
    }
    __syncthreads();

    for (int l = 0; l < 4; ++l) {
        const float2* bsl = bs + l * 20 * 146;
        const float2* sgl = sg + l * 10 * 36;
        for (int half = 0; half < 2; ++half) {
            const float2* bh = bsl + half * 10 * 146;
            // rail order k = {0,2,1,3,0,2,1,3,0,2}: m=gi%4, k=(m&1)*2+m/2
            for (int gi = 0; gi < 10; ++gi) {
                const float2* U = bh + gi * 146;
                const int m = gi & 3;
                const int k = ((m & 1) << 1) | (m >> 1);
                switch (k) {
                    case 0: apply2_bd<0>(U, psi, tid); break;
                    case 1: apply2_bd<1>(U, psi, tid); break;
                    case 2: apply2_bd<2>(U, psi, tid); break;
                    default: apply2_bd<3>(U, psi, tid); break;
                }
            }
            const float2* sh = sgl + half * 5 * 36;
            apply1_u<0>(sh + 0*36, psi, tid);
            apply1_u<1>(sh + 1*36, psi, tid);
            apply1_u<2>(sh + 2*36, psi, tid);
            apply1_u<3>(sh + 3*36, psi, tid);
            apply1_u<4>(sh + 4*36, psi, tid);
        }
    }

    // <psi| X psi> on modes 0,1
    float s0 = 0.f, s1 = 0.f;
    for (int f = tid; f < 1296; f += 256) {
        const int d0 = f / 216, r0 = f - d0*216;
        const int d1 = r0 / 36, r1 = r0 - d1*36;
        const int base0 = d0*222 + d1*37 + r1;     // spectators of mode 0
        #pragma unroll
        for (int j = 0; j < 5; ++j) {
            const float2 p0 = psi[base0 + j*1332];
            const float2 p1 = psi[base0 + (j+1)*1332];
            s0 = fmaf(sqrtf((float)(j+1)), fmaf(p0.y, p1.y, p0.x*p1.x), s0);
        }
        const int base1 = d0*1332 + d1*37 + r1;    // spectators of mode 1
        #pragma unroll
        for (int j = 0; j < 5; ++j) {
            const float2 p0 = psi[base1 + j*222];
            const float2 p1 = psi[base1 + (j+1)*222];
            s1 = fmaf(sqrtf((float)(j+1)), fmaf(p0.y, p1.y, p0.x*p1.x), s1);
        }
    }
    #pragma unroll
    for (int off = 32; off > 0; off >>= 1) {
        s0 += __shfl_down(s0, off, 64);
        s1 += __shfl_down(s1, off, 64);
    }
    if ((tid & 63) == 0) { red[(tid>>6)*2] = s0; red[(tid>>6)*2 + 1] = s1; }
    __syncthreads();
    if (tid == 0) {
        out[b*2 + 0] = 2.f*(red[0] + red[2] + red[4] + red[6]);
        out[b*2 + 1] = 2.f*(red[1] + red[3] + red[5] + red[7]);
    }
}

// ---------------------------------------------------------------------------
extern "C" void kernel_launch(void* const* d_in, const int* in_sizes, int n_in,
                              void* d_out, int out_size, void* d_ws, size_t ws_size,
                              hipStream_t stream)
{
    const float* x    = (const float*)d_in[0];   // (B, 5)
    const float* lin  = (const float*)d_in[1];   // (4, 63)
    const float* act  = (const float*)d_in[2];   // (3, 5)
    const float* lact = (const float*)d_in[3];   // (5,)
    float* out = (float*)d_out;                  // (B, 2) float32

    const int B = in_sizes[0] / 5;

    // ws layout: 80 packed BS gates (146 c64) | 40 single gates (36 c64) | dcol
    float2* bs = (float2*)d_ws;
    float2* sg = bs + 80*146;
    float*  dc = (float*)(sg + 40*36);

    gates_kernel<<<dim3(81), dim3(256), 0, stream>>>(lin, act, lact, bs, sg);
    const int total = B * 5;
    dcol_kernel<<<dim3((total + 255)/256), dim3(256), 0, stream>>>(x, dc, total);
    qnet_kernel<<<dim3(B), dim3(256), 0, stream>>>(bs, sg, dc, out);
}